// Round 8
// baseline (645.677 us; speedup 1.0000x reference)
//
#include <hip/hip_runtime.h>
#include <hip/hip_bf16.h>
#include <math.h>

typedef __hip_bfloat16 bf16;
typedef unsigned short u16;
typedef unsigned int   u32;
typedef __bf16  bf16x8 __attribute__((ext_vector_type(8)));
typedef float   f32x4  __attribute__((ext_vector_type(4)));

#define NTOK 100352   // 32 * 56 * 56
#define QSCALE 0.17677669529663687f

// branch-free GELU: erf via Abramowitz-Stegun 7.1.25 (|eps| <= 5e-4)
__device__ __forceinline__ float fast_gelu(float z) {
  const float t = fabsf(z) * 0.7071067811865476f;
  float p = fmaf(t, 0.078108f, 0.000972f);
  p = fmaf(t, p, 0.230389f);
  p = fmaf(t, p, 0.278393f);
  p = fmaf(t, p, 1.0f);
  p = p * p; p = p * p;                       // p^4  (p >= 1)
  const float e = 1.0f - __builtin_amdgcn_rcpf(p);   // erf(|z|/sqrt2)
  const float er = copysignf(e, z);
  return 0.5f * z * (1.0f + er);
}

// ---------------- merged fp32 -> bf16 transposes (weights, every launch) ----
__global__ __launch_bounds__(256)
void cvt_all(const float* __restrict__ qkv_w, const float* __restrict__ proj_w,
             const float* __restrict__ fc1_w, const float* __restrict__ fc2_w,
             bf16* __restrict__ wqkvT, bf16* __restrict__ wprojT,
             bf16* __restrict__ wfc1T, bf16* __restrict__ wfc2T)
{
  const int i = blockIdx.x * 256 + threadIdx.x;
  if (i < 196608) {
    const int k = i / 768, n = i % 768;
    wqkvT[n * 256 + k] = __float2bfloat16(qkv_w[i]);
  } else if (i < 262144) {
    const int j = i - 196608, k = j / 256, n = j % 256;
    wprojT[n * 256 + k] = __float2bfloat16(proj_w[j]);
  } else if (i < 524288) {
    const int j = i - 262144, k = j / 1024, n = j % 1024;
    wfc1T[n * 256 + k] = __float2bfloat16(fc1_w[j]);
  } else {
    const int j = i - 524288, k = j / 256, n = j % 256;
    wfc2T[n * 1024 + k] = __float2bfloat16(fc2_w[j]);
  }
}

// ---------------- pos-bias MLP + rel_bias table (1 block) ----------------
// rel_bias PADDED: [8 heads][49 rows][64 cols] (cols 49..63 = 0).
__device__ __forceinline__ void ln16_relu(float* cur, const float* g, const float* b) {
  float mu = 0.f;
#pragma unroll
  for (int j = 0; j < 16; ++j) mu += cur[j];
  mu *= (1.f / 16.f);
  float var = 0.f;
#pragma unroll
  for (int j = 0; j < 16; ++j) { float d = cur[j] - mu; var += d * d; }
  var *= (1.f / 16.f);
  const float r = rsqrtf(var + 1e-5f);
#pragma unroll
  for (int j = 0; j < 16; ++j) {
    float y = (cur[j] - mu) * r * g[j] + b[j];
    cur[j] = fmaxf(y, 0.f);
  }
}

__global__ __launch_bounds__(256)
void pos_kernel(const float* __restrict__ ppw, const float* __restrict__ ppb,
                const float* __restrict__ g1, const float* __restrict__ lb1,
                const float* __restrict__ w1, const float* __restrict__ b1,
                const float* __restrict__ g2, const float* __restrict__ lb2,
                const float* __restrict__ w2, const float* __restrict__ b2,
                const float* __restrict__ g3, const float* __restrict__ lb3,
                const float* __restrict__ w3, const float* __restrict__ b3,
                float* __restrict__ rel_bias)
{
  __shared__ float pos_s[169 * 8];
  const int t = threadIdx.x;
  if (t < 169) {
    float cur[16], nxt[16];
    const float bh = (float)(t / 13 - 6), bw = (float)(t % 13 - 6);
#pragma unroll
    for (int j = 0; j < 16; ++j)
      cur[j] = bh * ppw[j] + bw * ppw[16 + j] + ppb[j];
    ln16_relu(cur, g1, lb1);
    for (int j = 0; j < 16; ++j) nxt[j] = b1[j];
    for (int k = 0; k < 16; ++k) { float a = cur[k]; for (int j = 0; j < 16; ++j) nxt[j] += a * w1[k * 16 + j]; }
    for (int j = 0; j < 16; ++j) cur[j] = nxt[j];
    ln16_relu(cur, g2, lb2);
    for (int j = 0; j < 16; ++j) nxt[j] = b2[j];
    for (int k = 0; k < 16; ++k) { float a = cur[k]; for (int j = 0; j < 16; ++j) nxt[j] += a * w2[k * 16 + j]; }
    for (int j = 0; j < 16; ++j) cur[j] = nxt[j];
    ln16_relu(cur, g3, lb3);
    for (int h = 0; h < 8; ++h) {
      float s = b3[h];
      for (int k = 0; k < 16; ++k) s += cur[k] * w3[k * 8 + h];
      pos_s[t * 8 + h] = s;
    }
  }
  __syncthreads();
  for (int e = t; e < 8 * 49 * 64; e += 256) {
    const int h = e / 3136, ij = e % 3136, i = ij / 64, j = ij % 64;
    float val = 0.f;
    if (j < 49) {
      const int dh = i / 7 - j / 7 + 6, dw = i % 7 - j % 7 + 6;
      val = pos_s[(dh * 13 + dw) * 8 + h];
    }
    rel_bias[e] = val;
  }
}

// ---------------- LayerNorm over C=256: one wave per token (LN1 only) -----
__global__ __launch_bounds__(256)
void ln_wave(const float* __restrict__ xin,
             const float* __restrict__ g, const float* __restrict__ b,
             bf16* __restrict__ out)
{
  const int tok = blockIdx.x * 4 + (threadIdx.x >> 6);
  const int lane = threadIdx.x & 63;
  const float4 xv = *reinterpret_cast<const float4*>(xin + (size_t)tok * 256 + lane * 4);
  float s = xv.x + xv.y + xv.z + xv.w;
#pragma unroll
  for (int off = 1; off < 64; off <<= 1) s += __shfl_xor(s, off, 64);
  const float mu = s * (1.f / 256.f);
  const float4 dx = make_float4(xv.x - mu, xv.y - mu, xv.z - mu, xv.w - mu);
  float v = dx.x * dx.x + dx.y * dx.y + dx.z * dx.z + dx.w * dx.w;
#pragma unroll
  for (int off = 1; off < 64; off <<= 1) v += __shfl_xor(v, off, 64);
  const float rstd = rsqrtf(v * (1.f / 256.f) + 1e-5f);
  const float4 gv = *reinterpret_cast<const float4*>(g + lane * 4);
  const float4 bv = *reinterpret_cast<const float4*>(b + lane * 4);
  bf16 o0 = __float2bfloat16(dx.x * rstd * gv.x + bv.x);
  bf16 o1 = __float2bfloat16(dx.y * rstd * gv.y + bv.y);
  bf16 o2 = __float2bfloat16(dx.z * rstd * gv.z + bv.z);
  bf16 o3 = __float2bfloat16(dx.w * rstd * gv.w + bv.w);
  ushort4 st = make_ushort4(*(u16*)&o0, *(u16*)&o1, *(u16*)&o2, *(u16*)&o3);
  *reinterpret_cast<ushort4*>(out + (size_t)tok * 256 + lane * 4) = st;
}

// ---------------- MFMA GEMM: C[M,N] = A[M,K] @ BT[N,K]^T + epilogue ------
// BK=64, 128x128 tile, 4 waves.  XCD-aware flat-id swizzle (nwg%8==0).
// Staging LDS rows are 128B with a both-sides XOR swizzle.
// EPI 0 (bias->bf16) / 2 (bias+gelu->bf16): LDS-transposed bf16 store.
// EPI 3 (resF+bias->fp32): direct stores (fc2, final output).
template<int EPI>
__global__ __launch_bounds__(256, 3)
void gemm_mfma(const bf16* __restrict__ A, const bf16* __restrict__ BT,
               const float* __restrict__ bias, const float* __restrict__ resF,
               float* __restrict__ outF, bf16* __restrict__ outB,
               const int M, const int N, const int K)
{
  __shared__ __align__(16) u16 LdsAll[128 * 136];
  const int t = threadIdx.x;

  const int nwg = gridDim.x * gridDim.y;
  int f = blockIdx.y * gridDim.x + blockIdx.x;
  f = (f & 7) * (nwg >> 3) + (f >> 3);
  const int m0 = (f / gridDim.x) << 7;
  const int n0 = (f % gridDim.x) << 7;

  const int wave = t >> 6, lane = t & 63;
  const int quad = lane >> 4, l15 = lane & 15;
  const int mw = (wave & 1) << 6, nw = (wave >> 1) << 6;

  const int sr = t >> 3;              // 0..31
  const int sb = t & 7;
  const int scol = ((sb ^ (sr & 7)) << 3);
  const bf16* ag = A  + (size_t)(m0 + sr) * K + scol;
  const bf16* bg = BT + (size_t)(n0 + sr) * K + scol;
  char* alds = (char*)LdsAll + t * 16;
  char* blds = (char*)LdsAll + 16384 + t * 16;

  f32x4 acc[4][4];
#pragma unroll
  for (int mi = 0; mi < 4; ++mi)
#pragma unroll
    for (int ni = 0; ni < 4; ++ni) acc[mi][ni] = (f32x4){0.f, 0.f, 0.f, 0.f};

  const int rsw = (l15 & 7);

  for (int kt = 0; kt < K; kt += 64) {
#pragma unroll
    for (int p = 0; p < 4; ++p) {
      __builtin_amdgcn_global_load_lds(
          (const __attribute__((address_space(1))) void*)(ag + kt + (size_t)p * (K << 5)),
          (__attribute__((address_space(3))) void*)(alds + (p << 12)), 16, 0, 0);
      __builtin_amdgcn_global_load_lds(
          (const __attribute__((address_space(1))) void*)(bg + kt + (size_t)p * (K << 5)),
          (__attribute__((address_space(3))) void*)(blds + (p << 12)), 16, 0, 0);
    }
    __syncthreads();

#pragma unroll
    for (int kk = 0; kk < 2; ++kk) {
      const int blk = ((kk * 4 + quad) ^ rsw) << 4;
      bf16x8 af[4], bfr[4];
#pragma unroll
      for (int mi = 0; mi < 4; ++mi)
        af[mi] = *(const bf16x8*)((const char*)LdsAll + (mw + mi * 16 + l15) * 128 + blk);
#pragma unroll
      for (int ni = 0; ni < 4; ++ni)
        bfr[ni] = *(const bf16x8*)((const char*)LdsAll + 16384 + (nw + ni * 16 + l15) * 128 + blk);
#pragma unroll
      for (int mi = 0; mi < 4; ++mi)
#pragma unroll
        for (int ni = 0; ni < 4; ++ni)
          acc[mi][ni] = __builtin_amdgcn_mfma_f32_16x16x32_bf16(af[mi], bfr[ni], acc[mi][ni], 0, 0, 0);
    }
    __syncthreads();
  }

  if (EPI == 0 || EPI == 2) {
    float bv[4];
#pragma unroll
    for (int ni = 0; ni < 4; ++ni) bv[ni] = bias[n0 + nw + ni * 16 + l15];
#pragma unroll
    for (int mi = 0; mi < 4; ++mi) {
#pragma unroll
      for (int r = 0; r < 4; ++r) {
        const int row = mw + mi * 16 + quad * 4 + r;
#pragma unroll
        for (int ni = 0; ni < 4; ++ni) {
          const int col = nw + ni * 16 + l15;
          float z = acc[mi][ni][r] + bv[ni];
          if (EPI == 2) z = fast_gelu(z);
          const bf16 o = __float2bfloat16(z);
          LdsAll[row * 136 + col] = *(const u16*)&o;
        }
      }
    }
    __syncthreads();
    const int c16 = lane & 15;
    const int r4 = lane >> 4;
#pragma unroll
    for (int pass = 0; pass < 8; ++pass) {
      const int row = pass * 16 + wave * 4 + r4;
      const uint4 vv = *(const uint4*)((const char*)LdsAll + row * 272 + c16 * 16);
      *(uint4*)(outB + (size_t)(m0 + row) * N + n0 + c16 * 8) = vv;
    }
  } else {
#pragma unroll
    for (int mi = 0; mi < 4; ++mi) {
#pragma unroll
      for (int r = 0; r < 4; ++r) {
        const int m = m0 + mw + mi * 16 + quad * 4 + r;
#pragma unroll
        for (int ni = 0; ni < 4; ++ni) {
          const int n = n0 + nw + ni * 16 + l15;
          outF[(size_t)m * N + n] = resF[(size_t)m * N + n] + acc[mi][ni][r] + bias[n];
        }
      }
    }
  }
}

// ---------------- proj GEMM + residual + fused LayerNorm2 -----------------
// Tile 128x256 (full width), grid (1, NTOK/128).  Wave w owns rows
// [w*32, w*32+32) x all 256 cols: acc[2][16].  Each LN row lives in one
// 16-lane group (cols = ni*16 + l15) -> mean/var = in-lane adds + 4 shfl_xor.
// Writes xr = aout@W + bias + x (fp32, d_out) and yn = LN2(xr) (bf16) via a
// chunk-XOR-swizzled LDS transpose (conflict-free) + uint4 stores.
__global__ __launch_bounds__(256, 2)
void proj_ln(const bf16* __restrict__ A, const bf16* __restrict__ BT,
             const float* __restrict__ bias, const float* __restrict__ resF,
             const float* __restrict__ g2, const float* __restrict__ b2,
             float* __restrict__ xr, bf16* __restrict__ yn)
{
  // union: staging A[0,16K) + B[16K,48K); epilogue yn tile [128][264] u16
  __shared__ __align__(16) u16 L[128 * 264];   // 67584 B
  const int t = threadIdx.x;

  const int nwg = gridDim.y;                    // gridDim.x == 1
  int f = blockIdx.y;
  f = (f & 7) * (nwg >> 3) + (f >> 3);
  const int m0 = f << 7;

  const int wave = t >> 6, lane = t & 63;
  const int quad = lane >> 4, l15 = lane & 15;
  const int mw = wave << 5;                     // 32 rows per wave

  const int sr = t >> 3, sb = t & 7;
  const int scol = ((sb ^ (sr & 7)) << 3);
  const bf16* ag = A  + (size_t)(m0 + sr) * 256 + scol;
  const bf16* bg = BT + (size_t)sr * 256 + scol;
  char* alds = (char*)L + t * 16;
  char* blds = (char*)L + 16384 + t * 16;

  f32x4 acc[2][16];
#pragma unroll
  for (int mi = 0; mi < 2; ++mi)
#pragma unroll
    for (int ni = 0; ni < 16; ++ni) acc[mi][ni] = (f32x4){0.f, 0.f, 0.f, 0.f};

  const int rsw = (l15 & 7);

  for (int kt = 0; kt < 256; kt += 64) {
#pragma unroll
    for (int p = 0; p < 4; ++p)
      __builtin_amdgcn_global_load_lds(
          (const __attribute__((address_space(1))) void*)(ag + kt + (size_t)p * 8192),
          (__attribute__((address_space(3))) void*)(alds + (p << 12)), 16, 0, 0);
#pragma unroll
    for (int p = 0; p < 8; ++p)
      __builtin_amdgcn_global_load_lds(
          (const __attribute__((address_space(1))) void*)(bg + kt + (size_t)p * 8192),
          (__attribute__((address_space(3))) void*)(blds + (p << 12)), 16, 0, 0);
    __syncthreads();

#pragma unroll
    for (int kk = 0; kk < 2; ++kk) {
      const int blk = ((kk * 4 + quad) ^ rsw) << 4;
      bf16x8 af[2];
#pragma unroll
      for (int mi = 0; mi < 2; ++mi)
        af[mi] = *(const bf16x8*)((const char*)L + (mw + mi * 16 + l15) * 128 + blk);
#pragma unroll
      for (int ni = 0; ni < 16; ++ni) {
        const bf16x8 bfr = *(const bf16x8*)((const char*)L + 16384 + (ni * 16 + l15) * 128 + blk);
#pragma unroll
        for (int mi = 0; mi < 2; ++mi)
          acc[mi][ni] = __builtin_amdgcn_mfma_f32_16x16x32_bf16(af[mi], bfr, acc[mi][ni], 0, 0, 0);
      }
    }
    __syncthreads();
  }

  // epilogue: z = acc + bias + resF; xr = z; yn = LN(z)*g+b
  float bv[16], gv[16], b2v[16];
#pragma unroll
  for (int ni = 0; ni < 16; ++ni) {
    const int col = ni * 16 + l15;
    bv[ni] = bias[col];  gv[ni] = g2[col];  b2v[ni] = b2[col];
  }
#pragma unroll
  for (int mi = 0; mi < 2; ++mi) {
#pragma unroll
    for (int r = 0; r < 4; ++r) {
      const int row = mw + mi * 16 + quad * 4 + r;       // 0..127
      const size_t gm = (size_t)(m0 + row) * 256;
      float z[16];
      float s = 0.f;
#pragma unroll
      for (int ni = 0; ni < 16; ++ni) {
        z[ni] = acc[mi][ni][r] + bv[ni] + resF[gm + ni * 16 + l15];
        s += z[ni];
      }
#pragma unroll
      for (int off = 1; off < 16; off <<= 1) s += __shfl_xor(s, off, 64);
      const float mu = s * (1.f / 256.f);
      float v = 0.f;
#pragma unroll
      for (int ni = 0; ni < 16; ++ni) { const float d = z[ni] - mu; v += d * d; }
#pragma unroll
      for (int off = 1; off < 16; off <<= 1) v += __shfl_xor(v, off, 64);
      const float rstd = rsqrtf(v * (1.f / 256.f) + 1e-5f);
      const int sxor = ((row >> 2) & 3) << 1;
#pragma unroll
      for (int ni = 0; ni < 16; ++ni) {
        xr[gm + ni * 16 + l15] = z[ni];
        const float y = (z[ni] - mu) * rstd * gv[ni] + b2v[ni];
        const bf16 o = __float2bfloat16(y);
        const int col = ni * 16 + l15;
        const int chunk = (col >> 3) ^ sxor;
        L[row * 264 + (chunk << 3) + (col & 7)] = *(const u16*)&o;
      }
    }
  }
  __syncthreads();
  // readback + coalesced store: 128 rows x 32 chunks of 16B
  const int cc = t & 31, rr = t >> 5;
#pragma unroll
  for (int i = 0; i < 16; ++i) {
    const int row = rr + i * 8;
    const int sxor = ((row >> 2) & 3) << 1;
    const uint4 vv = *(const uint4*)((const char*)L + row * 528 + ((cc ^ sxor) << 4));
    *(uint4*)(yn + (size_t)(m0 + row) * 256 + cc * 8) = vv;
  }
}

// ---------------- MFMA attention v4: token-major QKV, transposed S ---------
__global__ __launch_bounds__(256)
void attn_mfma(const bf16* __restrict__ qkv, const float* __restrict__ rel_bias,
               bf16* __restrict__ out)
{
  __shared__ __align__(16) u16 Ps[4][64 * 72];
  __shared__ int toks[4][64];
  const int w = threadIdx.x >> 6;
  const int lane = threadIdx.x & 63;
  const int bid = (blockIdx.x << 2) | w;       // win*8 + head
  const int win = bid >> 3, head = bid & 7;
  const int quad = lane >> 4, l15 = lane & 15;
  const int hq = head * 32;
  u16* const myP = &Ps[w][0];

  {
    const int b = win >> 6, wh = (win >> 3) & 7, wwd = win & 7;
    const int winbase = b * 3136 + wh * 7 * 56 + wwd * 7;
    const int rc = lane < 49 ? lane : 48;
    toks[w][lane] = winbase + (rc / 7) * 56 + (rc % 7);
  }
  __syncthreads();

  bf16x8 qf[4], kf[4];
#pragma unroll
  for (int i = 0; i < 4; ++i) {
    const size_t rowb = (size_t)toks[w][i * 16 + l15] * 768 + hq + quad * 8;
    qf[i] = *(const bf16x8*)(qkv + rowb);
    kf[i] = *(const bf16x8*)(qkv + rowb + 256);
  }

  f32x4 St[4][4];
#pragma unroll
  for (int mi = 0; mi < 4; ++mi)
#pragma unroll
    for (int ni = 0; ni < 4; ++ni)
      St[mi][ni] = __builtin_amdgcn_mfma_f32_16x16x32_bf16(kf[mi], qf[ni],
                                                           (f32x4){0.f, 0.f, 0.f, 0.f}, 0, 0, 0);

  u16 vtmp[2][2][8];
#pragma unroll
  for (int kt = 0; kt < 2; ++kt)
#pragma unroll
    for (int jj = 0; jj < 8; ++jj) {
      const size_t rowb = (size_t)toks[w][kt * 32 + quad * 8 + jj] * 768 + 512 + hq;
#pragma unroll
      for (int ni = 0; ni < 2; ++ni)
        vtmp[kt][ni][jj] = *(const u16*)(qkv + rowb + ni * 16 + l15);
    }

  const float* rb = rel_bias + head * 3136;    // padded [49][64]
#pragma unroll
  for (int ni = 0; ni < 4; ++ni) {
    const int m = ni * 16 + l15;
    const int mc = m < 49 ? m : 48;
    const float* rbp = rb + mc * 64 + quad * 4;
    float sv[4][4];
#pragma unroll
    for (int mi = 0; mi < 4; ++mi) {
      const float4 rv = *(const float4*)(rbp + mi * 16);
      const float rvx[4] = {rv.x, rv.y, rv.z, rv.w};
#pragma unroll
      for (int r = 0; r < 4; ++r) {
        const int j = mi * 16 + quad * 4 + r;
        sv[mi][r] = (j < 49) ? fmaf(St[mi][ni][r], QSCALE, rvx[r]) : -3e38f;
      }
    }
    float mx0 = fmaxf(fmaxf(sv[0][0], sv[0][1]), fmaxf(sv[0][2], sv[0][3]));
    float mx1 = fmaxf(fmaxf(sv[1][0], sv[1][1]), fmaxf(sv[1][2], sv[1][3]));
    float mx2 = fmaxf(fmaxf(sv[2][0], sv[2][1]), fmaxf(sv[2][2], sv[2][3]));
    float mx3 = fmaxf(fmaxf(sv[3][0], sv[3][1]), fmaxf(sv[3][2], sv[3][3]));
    float mx = fmaxf(fmaxf(mx0, mx1), fmaxf(mx2, mx3));
    mx = fmaxf(mx, __shfl_xor(mx, 16, 64));
    mx = fmaxf(mx, __shfl_xor(mx, 32, 64));
    float sum = 0.f;
#pragma unroll
    for (int mi = 0; mi < 4; ++mi)
#pragma unroll
      for (int r = 0; r < 4; ++r) { sv[mi][r] = __expf(sv[mi][r] - mx); sum += sv[mi][r]; }
    sum += __shfl_xor(sum, 16, 64);
    sum += __shfl_xor(sum, 32, 64);
    const float inv = 1.f / sum;
#pragma unroll
    for (int mi = 0; mi < 4; ++mi) {
      bf16 p0 = __float2bfloat16(sv[mi][0] * inv);
      bf16 p1 = __float2bfloat16(sv[mi][1] * inv);
      bf16 p2 = __float2bfloat16(sv[mi][2] * inv);
      bf16 p3 = __float2bfloat16(sv[mi][3] * inv);
      const u32 a = (u32)*(u16*)&p0 | ((u32)*(u16*)&p1 << 16);
      const u32 b = (u32)*(u16*)&p2 | ((u32)*(u16*)&p3 << 16);
      *reinterpret_cast<uint2*>(myP + m * 72 + mi * 16 + quad * 4) = make_uint2(a, b);
    }
  }

  f32x4 O[4][2];
#pragma unroll
  for (int mi = 0; mi < 4; ++mi)
#pragma unroll
    for (int ni = 0; ni < 2; ++ni) O[mi][ni] = (f32x4){0.f, 0.f, 0.f, 0.f};
#pragma unroll
  for (int kt = 0; kt < 2; ++kt) {
    bf16x8 pf[4];
#pragma unroll
    for (int mi = 0; mi < 4; ++mi)
      pf[mi] = *(const bf16x8*)(myP + (mi * 16 + l15) * 72 + kt * 32 + quad * 8);
#pragma unroll
    for (int ni = 0; ni < 2; ++ni) {
      bf16x8 vf = *(const bf16x8*)&vtmp[kt][ni][0];
#pragma unroll
      for (int mi = 0; mi < 4; ++mi)
        O[mi][ni] = __builtin_amdgcn_mfma_f32_16x16x32_bf16(pf[mi], vf, O[mi][ni], 0, 0, 0);
    }
  }

#pragma unroll
  for (int mi = 0; mi < 4; ++mi) {
#pragma unroll
    for (int r = 0; r < 4; ++r) {
      const int m = mi * 16 + quad * 4 + r;
      if (m < 49) {
        bf16* op = out + (size_t)toks[w][m] * 256 + hq;
#pragma unroll
        for (int ni = 0; ni < 2; ++ni)
          op[ni * 16 + l15] = __float2bfloat16(O[mi][ni][r]);
      }
    }
  }
}

// ---------------- launch ----------------
extern "C" void kernel_launch(void* const* d_in, const int* in_sizes, int n_in,
                              void* d_out, int out_size, void* d_ws, size_t ws_size,
                              hipStream_t stream)
{
  const float* x      = (const float*)d_in[0];
  const float* n1g    = (const float*)d_in[1];
  const float* n1b    = (const float*)d_in[2];
  const float* qkv_w  = (const float*)d_in[3];
  const float* qkv_b  = (const float*)d_in[4];
  const float* proj_w = (const float*)d_in[5];
  const float* proj_b = (const float*)d_in[6];
  const float* pp_w   = (const float*)d_in[7];
  const float* pp_b   = (const float*)d_in[8];
  const float* p1g    = (const float*)d_in[9];
  const float* p1lb   = (const float*)d_in[10];
  const float* p1w    = (const float*)d_in[11];
  const float* p1b    = (const float*)d_in[12];
  const float* p2g    = (const float*)d_in[13];
  const float* p2lb   = (const float*)d_in[14];
  const float* p2w    = (const float*)d_in[15];
  const float* p2b    = (const float*)d_in[16];
  const float* p3g    = (const float*)d_in[17];
  const float* p3lb   = (const float*)d_in[18];
  const float* p3w    = (const float*)d_in[19];
  const float* p3b    = (const float*)d_in[20];
  const float* n2g    = (const float*)d_in[21];
  const float* n2b    = (const float*)d_in[22];
  const float* fc1_w  = (const float*)d_in[23];
  const float* fc1_b  = (const float*)d_in[24];
  const float* fc2_w  = (const float*)d_in[25];
  const float* fc2_b  = (const float*)d_in[26];

  const size_t REG = (size_t)NTOK * 256 * 2;   // 51,380,224
  char* ws = (char*)d_ws;
  float* rel_bias = (float*)ws;
  bf16* wqkvT = (bf16*)(ws + 131072);
  bf16* wprojT = wqkvT + 196608;
  bf16* wfc1T = wprojT + 65536;
  bf16* wfc2T = wfc1T + 262144;
  char* R1 = ws + (2 << 20);
  char* R2 = R1 + REG;
  char* R3 = R2 + REG;
  char* R4 = R3 + REG;

  bf16*  xn   = (bf16*)R1;        // phase 1
  bf16*  qkvb = (bf16*)R2;        // token-major [NTOK][768], spans R2..R4
  bf16*  aout = (bf16*)R1;        // phase 2 (xn dead)
  float* xr   = (float*)d_out;    // fp32 residual in the output buffer
  bf16*  yn   = (bf16*)R4;        // phase 3 (qkv dead after attn)
  bf16*  Hc   = (bf16*)R2;        // phase 4 — spans R2+R3

  cvt_all<<<3072, 256, 0, stream>>>(qkv_w, proj_w, fc1_w, fc2_w,
                                    wqkvT, wprojT, wfc1T, wfc2T);
  pos_kernel<<<1, 256, 0, stream>>>(pp_w, pp_b, p1g, p1lb, p1w, p1b,
                                    p2g, p2lb, p2w, p2b, p3g, p3lb, p3w, p3b, rel_bias);
  ln_wave<<<NTOK / 4, 256, 0, stream>>>(x, n1g, n1b, xn);
  gemm_mfma<0><<<dim3(6, NTOK / 128), 256, 0, stream>>>(xn, wqkvT, qkv_b, nullptr,
      nullptr, qkvb, NTOK, 768, 256);
  attn_mfma<<<4096, 256, 0, stream>>>(qkvb, rel_bias, aout);
  // fused proj + residual + LN2: writes xr (fp32) and yn (bf16)
  proj_ln<<<dim3(1, NTOK / 128), 256, 0, stream>>>(aout, wprojT, proj_b, x,
      n2g, n2b, xr, yn);

  // MLP in 2 M-chunks of 50176 tokens (hidden chunk = R2+R3):
  const int MC = 50176;
  for (int c = 0; c < 2; ++c) {
    const size_t mb = (size_t)c * MC;
    gemm_mfma<2><<<dim3(8, MC / 128), 256, 0, stream>>>(yn + mb * 256, wfc1T,
        fc1_b, nullptr, nullptr, Hc, MC, 1024, 256);
    gemm_mfma<3><<<dim3(2, MC / 128), 256, 0, stream>>>(Hc, wfc2T,
        fc2_b, xr + mb * 256, xr + mb * 256, nullptr, MC, 256, 1024);
  }
}